// Round 1
// baseline (424.613 us; speedup 1.0000x reference)
//
#include <hip/hip_runtime.h>

// Problem: B=4096, N=64, L=256, E=256, all fp32.
// d_in: 0=agent[B,L] 1=opp[B,N,L] 2=hard[B,N] 3=Ws[E,L] 4=Wt[E,L] 5=Wc[E,L]
// d_out: result[B,E] (1048576 f32) then scores[B,N] (262144 f32)
//
// Algebra: scores[b,n] = opp[b,n,:] @ M @ agent[b,:],  M[l,l'] = sum_e Wt[e,l]*Ws[e,l']
//          result[b,e] = sum_l Wc[e,l] * v[b,l],       v[b,l] = sum_n s[b,n]*opp[b,n,l]
//
// v2: double-buffered DMA mega-kernel. 512-thread block owns 16 b's (256 blocks =
// 1 block/CU exactly). LDS = 2x64KB opp double-buffer + 16KB V + 0.5KB = 144.5KB.
// Main loop issues DMA(i+1) into the free buffer, then waits a COUNTED
// s_waitcnt vmcnt(8) (i's 8 loads retired, i+1's 8 stay in flight) + raw s_barrier.
// __syncthreads is never used in the hot path (it drains vmcnt(0) and serializes
// DMA against compute — that stop-start duty cycle was the ~2x-over-floor cost).
// DMA(0) is issued before the prologue T-GEMM so the first 64KB hides under it.
// opp (256 MB) streamed exactly once => ~43 us HBM floor for mega.

#define Bsz 4096
#define Nn  64
#define Ll  256
#define Ee  256

#define BPB 16           // b's per block
#define TPB 512          // threads per block (8 waves)
#define TILE (Nn * Ll)   // 16384 floats = 64 KB per b

__device__ __forceinline__ void gload_lds16(const float4* g, float4* lds_base) {
  __builtin_amdgcn_global_load_lds(
      (const __attribute__((address_space(1))) unsigned int*)g,
      (__attribute__((address_space(3))) unsigned int*)lds_base,
      16, 0, 0);
}

// raw barrier that does NOT drain vmcnt: publish LDS writes (lgkmcnt) only.
#define LGKM0_BAR() do {                                  \
  asm volatile("s_waitcnt lgkmcnt(0)" ::: "memory");      \
  __builtin_amdgcn_s_barrier();                           \
  __builtin_amdgcn_sched_barrier(0);                      \
} while (0)

#define WAIT_VM(N) do {                                   \
  asm volatile("s_waitcnt vmcnt(" #N ")" ::: "memory");   \
  __builtin_amdgcn_sched_barrier(0);                      \
} while (0)

// ---------------- prep: MT[k][j] = M[j,k] = sum_e Ws[e,k]*Wt[e,j] ; WcT[l][e] = Wc[e,l]
__global__ __launch_bounds__(256) void prep_kernel(
    const float* __restrict__ Ws, const float* __restrict__ Wt,
    const float* __restrict__ Wc, float* __restrict__ MT, float* __restrict__ WcT) {
  int col = threadIdx.x;
  int row = blockIdx.x;
  if (row < 256) {
    float acc = 0.f;
    for (int e = 0; e < 256; ++e)
      acc = fmaf(Ws[e * 256 + row], Wt[e * 256 + col], acc);  // Ws uniform/blk, Wt coalesced
    MT[row * 256 + col] = acc;
  } else {
    int l = row - 256;
    WcT[l * 256 + col] = Wc[col * 256 + l];
  }
}

// ---------------- mega: per block, 16 b's end-to-end, DMA double-buffered.
__global__ __launch_bounds__(TPB, 2) void mega_kernel(
    const float* __restrict__ agent, const float* __restrict__ opp,
    const float* __restrict__ hard, const float* __restrict__ MT,
    const float* __restrict__ WcT, float* __restrict__ out,
    float* __restrict__ scores_out) {
  __shared__ float opp_s[2 * TILE];   // 128 KB double buffer
  __shared__ float V_s[BPB * Ll];     // 16 KB (prologue aliases it as agent staging)
  __shared__ float sraw[Nn];
  __shared__ float sfin[Nn];

  const int tid = threadIdx.x;
  const int lane = tid & 63;
  const int wave = tid >> 6;
  const int b0 = blockIdx.x * BPB;

  const int jq = lane;        // j = 4*jq .. 4*jq+3
  const int r0 = wave * 2;    // 2 local rows per wave (8 waves x 2 = 16 rows)

  // DMA issue for b-index bi into buffer buf: 8 x gload_lds16 per thread.
  // LDS dest is wave-uniform base + lane*16 (hardware scatter); global src per-lane.
  auto stage = [&](int bi, int buf) {
    const float4* o4 = (const float4*)(opp + (size_t)(b0 + bi) * TILE);
    float4* os4 = (float4*)(opp_s + buf * TILE);
#pragma unroll
    for (int k = 0; k < 8; ++k)
      gload_lds16(o4 + k * 512 + wave * 64 + lane, os4 + k * 512 + wave * 64);
  };

  // Kick off DMA(0) into buf0 immediately — hides under the prologue T-GEMM.
  stage(0, 0);

  // ======== prologue: T[r][j] = sum_k agent[b0+r][k] * MT[k*256+j], r=0..15
  // agent staged in V_s region (16 KB, dead until iter 0 writes V);
  // T_tmp in buf1 region (dead until DMA(1) lands, which is after tv reads).
  float* ag_s  = V_s;
  float* T_tmp = opp_s + TILE;
  {
    const float4* in4 = (const float4*)(agent + (size_t)b0 * 256);
    float4* s4 = (float4*)ag_s;
    s4[tid] = in4[tid];            // 16 rows x 64 float4 = 1024 float4, 2/thread
    s4[TPB + tid] = in4[TPB + tid];
    LGKM0_BAR();

    float4 a0 = {0.f, 0.f, 0.f, 0.f};
    float4 a1 = {0.f, 0.f, 0.f, 0.f};
    for (int k4 = 0; k4 < 64; ++k4) {
      const float4 w0 = ((const float4*)(MT + (k4 * 4 + 0) * 256))[jq];
      const float4 w1 = ((const float4*)(MT + (k4 * 4 + 1) * 256))[jq];
      const float4 w2 = ((const float4*)(MT + (k4 * 4 + 2) * 256))[jq];
      const float4 w3 = ((const float4*)(MT + (k4 * 4 + 3) * 256))[jq];
      const float4 v0 = ((const float4*)(ag_s + (r0 + 0) * 256))[k4];
      const float4 v1 = ((const float4*)(ag_s + (r0 + 1) * 256))[k4];
      a0.x = fmaf(v0.x, w0.x, fmaf(v0.y, w1.x, fmaf(v0.z, w2.x, fmaf(v0.w, w3.x, a0.x))));
      a0.y = fmaf(v0.x, w0.y, fmaf(v0.y, w1.y, fmaf(v0.z, w2.y, fmaf(v0.w, w3.y, a0.y))));
      a0.z = fmaf(v0.x, w0.z, fmaf(v0.y, w1.z, fmaf(v0.z, w2.z, fmaf(v0.w, w3.z, a0.z))));
      a0.w = fmaf(v0.x, w0.w, fmaf(v0.y, w1.w, fmaf(v0.z, w2.w, fmaf(v0.w, w3.w, a0.w))));
      a1.x = fmaf(v1.x, w0.x, fmaf(v1.y, w1.x, fmaf(v1.z, w2.x, fmaf(v1.w, w3.x, a1.x))));
      a1.y = fmaf(v1.x, w0.y, fmaf(v1.y, w1.y, fmaf(v1.z, w2.y, fmaf(v1.w, w3.y, a1.y))));
      a1.z = fmaf(v1.x, w0.z, fmaf(v1.y, w1.z, fmaf(v1.z, w2.z, fmaf(v1.w, w3.z, a1.z))));
      a1.w = fmaf(v1.x, w0.w, fmaf(v1.y, w1.w, fmaf(v1.z, w2.w, fmaf(v1.w, w3.w, a1.w))));
    }
    // T_tmp (buf1) is disjoint from ag_s (V_s region): no barrier needed before writes.
    ((float4*)(T_tmp + (r0 + 0) * 256))[jq] = a0;
    ((float4*)(T_tmp + (r0 + 1) * 256))[jq] = a1;
    LGKM0_BAR();
  }
  // tv[i] = T[b0+i][lane*4 .. +3] -> registers (64 VGPRs), then buf1 is free.
  float4 tv[BPB];
#pragma unroll
  for (int i = 0; i < BPB; ++i) tv[i] = ((const float4*)(T_tmp + i * 256))[lane];
  LGKM0_BAR();  // all tv reads retired before iter 0 issues DMA(1) into buf1

  // ======== main loop over 16 b's, double-buffered.
  // vmcnt bookkeeping (per wave): stage() = 8 loads. At iter i we issue i+1's 8,
  // then vmcnt(8) retires i's 8 (plus wave-0's scores store from iter i-1, which
  // sits between them in the queue and retires under the same wait — harmless).
#pragma unroll
  for (int i = 0; i < BPB; ++i) {
    float* cur = opp_s + (i & 1) * TILE;
    if (i < BPB - 1) {
      stage(i + 1, (i + 1) & 1);
      WAIT_VM(8);
    } else {
      WAIT_VM(0);
    }
    __builtin_amdgcn_s_barrier();           // all waves' DMA(i) portions visible
    __builtin_amdgcn_sched_barrier(0);

    // scores: wave w -> n = 8w..8w+7; 64-lane dot over l
    const float4 tvi = tv[i];
#pragma unroll
    for (int jj = 0; jj < 8; ++jj) {
      const int n = wave * 8 + jj;
      const float4 ov = ((const float4*)(cur + n * Ll))[lane];
      float p = ov.x * tvi.x + ov.y * tvi.y + ov.z * tvi.z + ov.w * tvi.w;
#pragma unroll
      for (int off = 32; off; off >>= 1) p += __shfl_down(p, off, 64);
      if (lane == 0) sraw[n] = p;
    }
    LGKM0_BAR();

    // softmax * hard (wave 0 only)
    if (tid < 64) {
      const float x = sraw[tid];
      float m = x;
#pragma unroll
      for (int off = 32; off; off >>= 1) m = fmaxf(m, __shfl_xor(m, off, 64));
      const float e = __expf(x - m);
      float s = e;
#pragma unroll
      for (int off = 32; off; off >>= 1) s += __shfl_xor(s, off, 64);
      const float val = e / s * hard[(size_t)(b0 + i) * Nn + tid];
      sfin[tid] = val;
      scores_out[(size_t)(b0 + i) * Nn + tid] = val;
    }
    LGKM0_BAR();

    // v[b,l] -> V_s: thread l = tid (first 4 waves); conflict-free, sfin broadcast
    if (tid < Ll) {
      float acc = 0.f;
#pragma unroll
      for (int n = 0; n < Nn; ++n) acc = fmaf(sfin[n], cur[n * Ll + tid], acc);
      V_s[i * Ll + tid] = acc;
    }
    LGKM0_BAR();  // cur reads retired (next iter DMAs into it); V_s[i] published
  }

  // ======== epilogue: out[b0+r][j] = sum_l V_s[r][l] * WcT[l*256+j], r=0..15
  {
    float4 a0 = {0.f, 0.f, 0.f, 0.f};
    float4 a1 = {0.f, 0.f, 0.f, 0.f};
    for (int k4 = 0; k4 < 64; ++k4) {
      const float4 w0 = ((const float4*)(WcT + (k4 * 4 + 0) * 256))[jq];
      const float4 w1 = ((const float4*)(WcT + (k4 * 4 + 1) * 256))[jq];
      const float4 w2 = ((const float4*)(WcT + (k4 * 4 + 2) * 256))[jq];
      const float4 w3 = ((const float4*)(WcT + (k4 * 4 + 3) * 256))[jq];
      const float4 v0 = ((const float4*)(V_s + (r0 + 0) * 256))[k4];
      const float4 v1 = ((const float4*)(V_s + (r0 + 1) * 256))[k4];
      a0.x = fmaf(v0.x, w0.x, fmaf(v0.y, w1.x, fmaf(v0.z, w2.x, fmaf(v0.w, w3.x, a0.x))));
      a0.y = fmaf(v0.x, w0.y, fmaf(v0.y, w1.y, fmaf(v0.z, w2.y, fmaf(v0.w, w3.y, a0.y))));
      a0.z = fmaf(v0.x, w0.z, fmaf(v0.y, w1.z, fmaf(v0.z, w2.z, fmaf(v0.w, w3.z, a0.z))));
      a0.w = fmaf(v0.x, w0.w, fmaf(v0.y, w1.w, fmaf(v0.z, w2.w, fmaf(v0.w, w3.w, a0.w))));
      a1.x = fmaf(v1.x, w0.x, fmaf(v1.y, w1.x, fmaf(v1.z, w2.x, fmaf(v1.w, w3.x, a1.x))));
      a1.y = fmaf(v1.x, w0.y, fmaf(v1.y, w1.y, fmaf(v1.z, w2.y, fmaf(v1.w, w3.y, a1.y))));
      a1.z = fmaf(v1.x, w0.z, fmaf(v1.y, w1.z, fmaf(v1.z, w2.z, fmaf(v1.w, w3.z, a1.z))));
      a1.w = fmaf(v1.x, w0.w, fmaf(v1.y, w1.w, fmaf(v1.z, w2.w, fmaf(v1.w, w3.w, a1.w))));
    }
    ((float4*)(out + (size_t)(b0 + r0 + 0) * 256))[jq] = a0;
    ((float4*)(out + (size_t)(b0 + r0 + 1) * 256))[jq] = a1;
  }
}

extern "C" void kernel_launch(void* const* d_in, const int* in_sizes, int n_in,
                              void* d_out, int out_size, void* d_ws, size_t ws_size,
                              hipStream_t stream) {
  const float* agent = (const float*)d_in[0];
  const float* opp   = (const float*)d_in[1];
  const float* hard  = (const float*)d_in[2];
  const float* Ws    = (const float*)d_in[3];
  const float* Wt    = (const float*)d_in[4];
  const float* Wc    = (const float*)d_in[5];

  float* out = (float*)d_out;                  // result [B,E]
  float* scores_out = out + (size_t)Bsz * Ee;  // scores [B,N]

  float* ws  = (float*)d_ws;
  float* MT  = ws;             // 65536 floats
  float* WcT = MT + 65536;     // 65536 floats

  prep_kernel<<<512, 256, 0, stream>>>(Ws, Wt, Wc, MT, WcT);
  mega_kernel<<<Bsz / BPB, TPB, 0, stream>>>(agent, opp, hard, MT, WcT, out, scores_out);
}